// Round 13
// baseline (249.374 us; speedup 1.0000x reference)
//
#include <hip/hip_runtime.h>
#include <math.h>

#define MM 16384
#define NN 8192
#define DD 128

#define L2E  1.4426950408889634f
#define COEF 0.15915494309189535f   // 1/(2*pi)

// ---------------------------------------------------------------------------
// fp16 helpers (RNE via v_cvt_f16_f32)
// ---------------------------------------------------------------------------
__device__ __forceinline__ unsigned short f2h(float f) {
    _Float16 h = (_Float16)f;
    unsigned short u;
    __builtin_memcpy(&u, &h, 2);
    return u;
}

__device__ __forceinline__ void async16(short* lds, const short* g) {
    __builtin_amdgcn_global_load_lds(
        (const __attribute__((address_space(1))) unsigned int*)g,
        (__attribute__((address_space(3))) unsigned int*)lds,
        16, 0, 0);
}

typedef __attribute__((ext_vector_type(8))) _Float16 f16x8;
typedef __attribute__((ext_vector_type(4))) float f32x4;

// ---------------------------------------------------------------------------
// Pre-pass v5 (unchanged, proven) — one 16-row block per 256-thread block.
// Cat = [rowblock rb][chunk 0..3][64 granules of 16B], granule (rp,gk) at
// slot rp*4+((gk+(rp>>1))&3); main kernel reads with the matching rdo
// permutation. A = fp16(x*L2E), B = fp16(mu) (dedup).
// dot = ah*bh; dropped a*bl AND al*bh (measured absmax 2.5e-29 vs threshold
// 2.8e-27, ~110x margin).
// xc[m] = -0.5|x|^2*L2E ; mc[n] = (ln w - 0.5|mu|^2)*L2E
// ---------------------------------------------------------------------------
__global__ __launch_bounds__(256) void gmm_prep_f16(
    const float* __restrict__ x, const float* __restrict__ means,
    const float* __restrict__ w, short* __restrict__ Acat,
    short* __restrict__ Bcat, float* __restrict__ xc, float* __restrict__ mc)
{
    const int tid  = threadIdx.x;
    const int rbk  = blockIdx.x;               // 0..1535
    const bool isx = rbk < (MM / 16);
    const int rb   = isx ? rbk : rbk - (MM / 16);
    const int lane = tid & 63;
    const int rp   = (tid >> 6) * 4 + (lane >> 4);   // 0..15 row in block
    const int cg   = lane & 15;                      // col granule 0..15
    const int p    = cg >> 2;                        // chunk 0..3
    const int gk   = cg & 3;
    const int row  = rb * 16 + rp;

    const float* src = (isx ? x : means) + (size_t)row * DD + cg * 8;
    float4 u0 = ((const float4*)src)[0];
    float4 u1 = ((const float4*)src)[1];
    float a[8] = {u0.x, u0.y, u0.z, u0.w, u1.x, u1.y, u1.z, u1.w};

    float ss = 0.f;
    unsigned hi[4];
    #pragma unroll
    for (int q = 0; q < 4; ++q) {
        ss = fmaf(a[2 * q], a[2 * q], fmaf(a[2 * q + 1], a[2 * q + 1], ss));
        float a0 = isx ? a[2 * q] * L2E     : a[2 * q];
        float a1 = isx ? a[2 * q + 1] * L2E : a[2 * q + 1];
        hi[q] = (unsigned)f2h(a0) | ((unsigned)f2h(a1) << 16);
    }
    uint4 HI = make_uint4(hi[0], hi[1], hi[2], hi[3]);

    const int slot = rp * 4 + ((gk + (rp >> 1)) & 3);    // bank swizzle
    short* base = (isx ? Acat : Bcat) + (size_t)rb * 2048 + p * 512 + slot * 8;
    *(uint4*)base = HI;

    ss += __shfl_xor(ss, 1, 16);
    ss += __shfl_xor(ss, 2, 16);
    ss += __shfl_xor(ss, 4, 16);
    ss += __shfl_xor(ss, 8, 16);
    if (cg == 0) {
        if (isx) xc[row] = -0.5f * ss * L2E;
        else     mc[row] = (logf(w[row]) - 0.5f * ss) * L2E;
    }
}

// ---------------------------------------------------------------------------
// Main MFMA kernel — v24: PERSISTENT-N blocks. One block = 8 consecutive
// 128x128 tiles (grid 128x8 = 1024 blocks) in ONE continuous 32-group
// counted-vmcnt pipeline (v17's proven contract, mechanically extended):
// group g = (nt=g>>2, ck=g&3) -> buffer g%3; 2 DMAs/wave/group (A rowblock w,
// B rowblock w of tile nt); phase p: vmcnt(2) [retires group p], s_barrier,
// issue group p+2, 8 MFMAs from buffer p%3; vmcnt(0) ONLY at p=31.
// WAR: group p+2 targets buffer (p+2)%3 = (p-1)%3, read in phase p-1,
// complete before barrier p. Pipeline fills ONCE per block (1024 vs 4096).
// Per-wave tile 64x32 -> acc = 32 AGPR, freeing regs for mcv[8][2] and
// rowAcc[4][4]: each tile's exp2 burst (at ck==3) accumulates into REGISTERS
// while the next tile's DMAs fly (T15 overlap); the S-matrix/red LDS
// epilogue (96 KB traffic + 3 barriers/block) is deleted. Final: 4-step
// shfl over col lanes + 512 atomics/block (32/address, proven level).
// Const loads (mcv,xa) consumed + vmcnt(0) drain BEFORE any DMA.
// LDS 48 KB ({A 8K | B 8K} x 3); launch_bounds(512,4) caps 128 regs.
// ---------------------------------------------------------------------------
__global__ __launch_bounds__(512, 4) void gmm_mfma(
    const short* __restrict__ Acat, const short* __restrict__ Bcat,
    const float* __restrict__ xc, const float* __restrict__ mc,
    float* __restrict__ out)
{
    __shared__ __align__(16) short smem[24576];   // 48 KB

#define AS(b) (smem + (b) * 4096)
#define BS(b) (smem + 12288 + (b) * 4096)

    const int tid  = threadIdx.x;
    const int w    = tid >> 6, lane = tid & 63;   // w 0..7
    const int wm   = w >> 2,   wn   = w & 3;      // 2 x 4 wave grid
    const int quad = lane >> 4, col = lane & 15;
    const int m0   = blockIdx.x * 128;
    const int nb   = blockIdx.y * 1024;           // 8 tiles x 128 cols

    // staging sources: wave w owns A rowblock w and B rowblock w (per tile)
    const short* ga = Acat + (size_t)(blockIdx.x * 8 + w) * 2048 + lane * 8;
    const short* gb = Bcat + (size_t)(blockIdx.y * 64 + w) * 2048 + lane * 8;
    const int ofs = w * 512;

    // const loads consumed into registers BEFORE any DMA (in-loop vmcnt then
    // counts staging groups only)
    float mcv[8][2];
    #pragma unroll
    for (int nt = 0; nt < 8; ++nt)
        #pragma unroll
        for (int j = 0; j < 2; ++j)
            mcv[nt][j] = mc[nb + nt * 128 + wn * 32 + j * 16 + col];
    float xa[4][4];
    #pragma unroll
    for (int i = 0; i < 4; ++i) {
        float4 xv = *(const float4*)(xc + m0 + wm * 64 + i * 16 + quad * 4);
        xa[i][0] = xv.x; xa[i][1] = xv.y; xa[i][2] = xv.z; xa[i][3] = xv.w;
    }
    float rowAcc[4][4];
    #pragma unroll
    for (int i = 0; i < 4; ++i)
        #pragma unroll
        for (int r = 0; r < 4; ++r) rowAcc[i][r] = 0.f;

    // drain const loads -> vmcnt==0 entering the pipeline
    asm volatile("s_waitcnt vmcnt(0)" ::: "memory");
    __builtin_amdgcn_sched_barrier(0);

    // prologue: groups 0 and 1 (2 DMAs each; 4 outstanding)
    async16(AS(0) + ofs, ga);
    async16(BS(0) + ofs, gb);
    async16(AS(1) + ofs, ga + 512);
    async16(BS(1) + ofs, gb + 512);

    // swizzled in-tile read offset (shorts): r'=col, g=quad
    const int rdo = col * 32 + ((quad + (col >> 1)) & 3) * 8;

    f32x4 acc[4][2];

    #pragma unroll
    for (int p = 0; p < 32; ++p) {
        const int nt = p >> 2, ck = p & 3;
        // wait: group p landed (outstanding {p, p+1} = 4 DMAs -> vmcnt(2));
        // last phase drains everything.
        if (p < 31) { asm volatile("s_waitcnt vmcnt(2)" ::: "memory"); }
        else        { asm volatile("s_waitcnt vmcnt(0)" ::: "memory"); }
        __builtin_amdgcn_sched_barrier(0);
        __builtin_amdgcn_s_barrier();
        __builtin_amdgcn_sched_barrier(0);
        if (p + 2 < 32) {
            const int g = p + 2, b = g % 3, gnt = g >> 2, gck = g & 3;
            async16(AS(b) + ofs, ga + gck * 512);
            async16(BS(b) + ofs, gb + (size_t)gnt * 16384 + gck * 512);
        }
        if (ck == 0) {   // new tile: acc init = xa[r] + mcv[nt][j]
            #pragma unroll
            for (int i = 0; i < 4; ++i)
                #pragma unroll
                for (int j = 0; j < 2; ++j)
                    acc[i][j] = (f32x4){xa[i][0] + mcv[nt][j],
                                        xa[i][1] + mcv[nt][j],
                                        xa[i][2] + mcv[nt][j],
                                        xa[i][3] + mcv[nt][j]};
        }
        {
            const int cb = p % 3;
            const short* as = AS(cb);
            const short* bs = BS(cb);
            f16x8 af[4];
            #pragma unroll
            for (int i = 0; i < 4; ++i)
                af[i] = *(const f16x8*)(as + (wm * 4 + i) * 512 + rdo);
            #pragma unroll
            for (int j = 0; j < 2; ++j) {
                f16x8 bfr = *(const f16x8*)(&bs[(wn * 2 + j) * 512 + rdo]);
                #pragma unroll
                for (int i = 0; i < 4; ++i)
                    acc[i][j] = __builtin_amdgcn_mfma_f32_16x16x32_f16(
                        af[i], bfr, acc[i][j], 0, 0, 0);
            }
        }
        if (ck == 3) {   // tile complete: exp2 burst -> register rowAcc
                         // (overlaps the in-flight DMAs of tiles nt+1/nt+2)
            #pragma unroll
            for (int i = 0; i < 4; ++i)
                #pragma unroll
                for (int r = 0; r < 4; ++r)
                    rowAcc[i][r] += __builtin_exp2f(acc[i][0][r])
                                  + __builtin_exp2f(acc[i][1][r]);
        }
    }

    // ---- epilogue: shfl-reduce over the 16 col lanes, fused atomic ----
    // rowAcc[i][r] = sum over (8 tiles x 2 j) of this thread's cols; the
    // remaining n-partials for row m live across col (lane bits 0..3) and
    // the 4 wn waves -> 4 shfl steps + 4 atomics per m per block.
    #pragma unroll
    for (int i = 0; i < 4; ++i) {
        #pragma unroll
        for (int r = 0; r < 4; ++r) {
            float v = rowAcc[i][r];
            v += __shfl_xor(v, 1, 16);
            v += __shfl_xor(v, 2, 16);
            v += __shfl_xor(v, 4, 16);
            v += __shfl_xor(v, 8, 16);
            if (col == 0)
                atomicAdd(out + m0 + wm * 64 + i * 16 + quad * 4 + r,
                          COEF * v);
        }
    }
#undef AS
#undef BS
}

// ===========================================================================
// Fallback fp32 path (round-1) — only if ws_size is too small.
// ===========================================================================
__global__ __launch_bounds__(256) void gmm_prep(
    const float* __restrict__ x, const float* __restrict__ means,
    const float* __restrict__ w, float* __restrict__ xc, float* __restrict__ mc)
{
    int tid = blockIdx.x * 256 + threadIdx.x;
    if (tid < MM) {
        const float4* row = (const float4*)(x + (size_t)tid * DD);
        float ss = 0.f;
        #pragma unroll
        for (int i = 0; i < DD / 4; ++i) {
            float4 v = row[i];
            ss = fmaf(v.x, v.x, fmaf(v.y, v.y, fmaf(v.z, v.z, fmaf(v.w, v.w, ss))));
        }
        xc[tid] = -0.5f * ss * L2E;
    } else if (tid < MM + NN) {
        int n = tid - MM;
        const float4* row = (const float4*)(means + (size_t)n * DD);
        float ss = 0.f;
        #pragma unroll
        for (int i = 0; i < DD / 4; ++i) {
            float4 v = row[i];
            ss = fmaf(v.x, v.x, fmaf(v.y, v.y, fmaf(v.z, v.z, fmaf(v.w, v.w, ss))));
        }
        mc[n] = (logf(w[n]) - 0.5f * ss) * L2E;
    }
}

__global__ __launch_bounds__(256, 2) void gmm_main(
    const float* __restrict__ x, const float* __restrict__ means,
    const float* __restrict__ xc, const float* __restrict__ mc,
    float* __restrict__ out)
{
    __shared__ __align__(16) float Asm[128 * 128];
    __shared__ __align__(16) float Bsm[2][16 * 128];

    const int t   = threadIdx.x;
    const int tc  = t & 15;
    const int tr  = t >> 4;
    const int r0  = blockIdx.x * 128;
    const int nq0 = blockIdx.y * 2048;

    {
        float4 tmp[16];
        #pragma unroll
        for (int ii = 0; ii < 16; ++ii) {
            int idx = t + ii * 256;
            int r   = idx >> 5;
            int k0  = (idx & 31) << 2;
            tmp[ii] = *(const float4*)(x + (size_t)(r0 + r) * DD + k0);
        }
        #pragma unroll
        for (int ii = 0; ii < 16; ++ii) {
            int idx = t + ii * 256;
            int r   = idx >> 5;
            int k0  = (idx & 31) << 2;
            int rb  = r >> 3, rl = r & 7;
            float v[4] = {tmp[ii].x, tmp[ii].y, tmp[ii].z, tmp[ii].w};
            #pragma unroll
            for (int j = 0; j < 4; ++j) {
                int k = k0 + j;
                Asm[k * 128 + (((rb ^ (k & 15)) << 3) | rl)] = v[j];
            }
        }
    }

    float xcv[8];
    {
        float4 a = *(const float4*)(xc + r0 + tr * 8);
        float4 b = *(const float4*)(xc + r0 + tr * 8 + 4);
        xcv[0] = a.x; xcv[1] = a.y; xcv[2] = a.z; xcv[3] = a.w;
        xcv[4] = b.x; xcv[5] = b.y; xcv[6] = b.z; xcv[7] = b.w;
    }

    float rowAcc[8];
    #pragma unroll
    for (int i = 0; i < 8; ++i) rowAcc[i] = 0.f;

    for (int ntile = 0; ntile < 16; ++ntile) {
        const int nbase = nq0 + ntile * 128;

        float acc[8][8];
        #pragma unroll
        for (int i = 0; i < 8; ++i)
            #pragma unroll
            for (int j = 0; j < 8; ++j) acc[i][j] = 0.f;

        float4 ld[2];
        #pragma unroll
        for (int ii = 0; ii < 2; ++ii) {
            int flat = t + ii * 256;
            int nl   = flat >> 2;
            int kl   = (flat & 3) << 2;
            ld[ii] = *(const float4*)(means + (size_t)(nbase + nl) * DD + kl);
        }

        for (int ks = 0; ks < 8; ++ks) {
            const int buf = ks & 1;
            #pragma unroll
            for (int ii = 0; ii < 2; ++ii) {
                int flat = t + ii * 256;
                int nl   = flat >> 2;
                int k0   = (flat & 3) << 2;
                int nbk  = nl >> 3, nll = nl & 7;
                float v[4] = {ld[ii].x, ld[ii].y, ld[ii].z, ld[ii].w};
                #pragma unroll
                for (int j = 0; j < 4; ++j) {
                    int kl = k0 + j;
                    Bsm[buf][kl * 128 + (((nbk ^ kl) << 3) | nll)] = v[j];
                }
            }
            if (ks < 7) {
                #pragma unroll
                for (int ii = 0; ii < 2; ++ii) {
                    int flat = t + ii * 256;
                    int nl   = flat >> 2;
                    int kl   = (flat & 3) << 2;
                    ld[ii] = *(const float4*)(means + (size_t)(nbase + nl) * DD
                                              + (ks + 1) * 16 + kl);
                }
            }
            __syncthreads();

            #pragma unroll
            for (int kk = 0; kk < 16; ++kk) {
                const int k = ks * 16 + kk;
                const float* apx = &Asm[k * 128 + ((tr ^ kk) << 3)];
                float4 a0 = *(const float4*)apx;
                float4 a1 = *(const float4*)(apx + 4);
                const float* bpx = &Bsm[buf][kk * 128 + ((tc ^ kk) << 3)];
                float4 b0 = *(const float4*)bpx;
                float4 b1 = *(const float4*)(bpx + 4);
                float av[8] = {a0.x, a0.y, a0.z, a0.w, a1.x, a1.y, a1.z, a1.w};
                float bv[8] = {b0.x, b0.y, b0.z, b0.w, b1.x, b1.y, b1.z, b1.w};
                #pragma unroll
                for (int i = 0; i < 8; ++i)
                    #pragma unroll
                    for (int j = 0; j < 8; ++j)
                        acc[i][j] = fmaf(av[i], bv[j], acc[i][j]);
            }
        }

        float mcv[8];
        {
            float4 a = *(const float4*)(mc + nbase + tc * 8);
            float4 b = *(const float4*)(mc + nbase + tc * 8 + 4);
            mcv[0] = a.x; mcv[1] = a.y; mcv[2] = a.z; mcv[3] = a.w;
            mcv[4] = b.x; mcv[5] = b.y; mcv[6] = b.z; mcv[7] = b.w;
        }
        #pragma unroll
        for (int i = 0; i < 8; ++i) {
            float s = 0.f;
            #pragma unroll
            for (int j = 0; j < 8; ++j) {
                float arg = fmaf(acc[i][j], L2E, xcv[i] + mcv[j]);
                s += __builtin_exp2f(arg);
            }
            rowAcc[i] += s;
        }
    }

    #pragma unroll
    for (int i = 0; i < 8; ++i) {
        float v = rowAcc[i];
        v += __shfl_xor(v, 1, 16);
        v += __shfl_xor(v, 2, 16);
        v += __shfl_xor(v, 4, 16);
        v += __shfl_xor(v, 8, 16);
        if (tc == 0) atomicAdd(out + r0 + tr * 8 + i, COEF * v);
    }
}

extern "C" void kernel_launch(void* const* d_in, const int* in_sizes, int n_in,
                              void* d_out, int out_size, void* d_ws, size_t ws_size,
                              hipStream_t stream) {
    const float* x     = (const float*)d_in[0];
    const float* means = (const float*)d_in[1];
    const float* w     = (const float*)d_in[2];
    float* out = (float*)d_out;

    const size_t needA = (size_t)MM * 128 * sizeof(short);   // 4.2 MB
    const size_t needB = (size_t)NN * 128 * sizeof(short);   // 2.1 MB (dedup)
    const size_t need  = needA + needB + (size_t)(MM + NN) * 4;

    if (ws_size >= need) {
        short* Acat = (short*)d_ws;
        short* Bcat = Acat + (size_t)MM * 128;
        float* xc   = (float*)(Bcat + (size_t)NN * 128);
        float* mc   = xc + MM;
        hipMemsetAsync(out, 0, MM * sizeof(float), stream);
        gmm_prep_f16<<<(MM + NN) / 16, 256, 0, stream>>>(x, means, w, Acat, Bcat, xc, mc);
        gmm_mfma<<<dim3(MM / 128, NN / 1024), 512, 0, stream>>>(Acat, Bcat, xc, mc, out);
    } else {
        float* xc = (float*)d_ws;
        float* mc = xc + MM;
        hipMemsetAsync(out, 0, MM * sizeof(float), stream);
        gmm_prep<<<(MM + NN + 255) / 256, 256, 0, stream>>>(x, means, w, xc, mc);
        gmm_main<<<dim3(MM / 128, 4), 256, 0, stream>>>(x, means, xc, mc, out);
    }
}

// Round 14
// 119.120 us; speedup vs baseline: 2.0935x; 2.0935x over previous
//
#include <hip/hip_runtime.h>
#include <math.h>

#define MM 16384
#define NN 8192
#define DD 128

#define L2E  1.4426950408889634f
#define COEF 0.15915494309189535f   // 1/(2*pi)

// ---------------------------------------------------------------------------
// fp16 helpers (RNE via v_cvt_f16_f32)
// ---------------------------------------------------------------------------
__device__ __forceinline__ unsigned short f2h(float f) {
    _Float16 h = (_Float16)f;
    unsigned short u;
    __builtin_memcpy(&u, &h, 2);
    return u;
}

__device__ __forceinline__ void async16(short* lds, const short* g) {
    __builtin_amdgcn_global_load_lds(
        (const __attribute__((address_space(1))) unsigned int*)g,
        (__attribute__((address_space(3))) unsigned int*)lds,
        16, 0, 0);
}

typedef __attribute__((ext_vector_type(8))) _Float16 f16x8;
typedef __attribute__((ext_vector_type(4))) float f32x4;

// ---------------------------------------------------------------------------
// Pre-pass v5 (unchanged, proven) — one 16-row block per 256-thread block.
// Cat = [rowblock rb][chunk 0..3][64 granules of 16B], granule (rp,gk) at
// slot rp*4+((gk+(rp>>1))&3); main kernel reads with the matching rdo
// permutation. A = fp16(x*L2E), B = fp16(mu) (dedup).
// dot = ah*bh; dropped a*bl AND al*bh (measured absmax 2.5e-29 vs threshold
// 2.8e-27, ~110x margin).
// xc[m] = -0.5|x|^2*L2E ; mc[n] = (ln w - 0.5|mu|^2)*L2E
// ---------------------------------------------------------------------------
__global__ __launch_bounds__(256) void gmm_prep_f16(
    const float* __restrict__ x, const float* __restrict__ means,
    const float* __restrict__ w, short* __restrict__ Acat,
    short* __restrict__ Bcat, float* __restrict__ xc, float* __restrict__ mc)
{
    const int tid  = threadIdx.x;
    const int rbk  = blockIdx.x;               // 0..1535
    const bool isx = rbk < (MM / 16);
    const int rb   = isx ? rbk : rbk - (MM / 16);
    const int lane = tid & 63;
    const int rp   = (tid >> 6) * 4 + (lane >> 4);   // 0..15 row in block
    const int cg   = lane & 15;                      // col granule 0..15
    const int p    = cg >> 2;                        // chunk 0..3
    const int gk   = cg & 3;
    const int row  = rb * 16 + rp;

    const float* src = (isx ? x : means) + (size_t)row * DD + cg * 8;
    float4 u0 = ((const float4*)src)[0];
    float4 u1 = ((const float4*)src)[1];
    float a[8] = {u0.x, u0.y, u0.z, u0.w, u1.x, u1.y, u1.z, u1.w};

    float ss = 0.f;
    unsigned hi[4];
    #pragma unroll
    for (int q = 0; q < 4; ++q) {
        ss = fmaf(a[2 * q], a[2 * q], fmaf(a[2 * q + 1], a[2 * q + 1], ss));
        float a0 = isx ? a[2 * q] * L2E     : a[2 * q];
        float a1 = isx ? a[2 * q + 1] * L2E : a[2 * q + 1];
        hi[q] = (unsigned)f2h(a0) | ((unsigned)f2h(a1) << 16);
    }
    uint4 HI = make_uint4(hi[0], hi[1], hi[2], hi[3]);

    const int slot = rp * 4 + ((gk + (rp >> 1)) & 3);    // bank swizzle
    short* base = (isx ? Acat : Bcat) + (size_t)rb * 2048 + p * 512 + slot * 8;
    *(uint4*)base = HI;

    ss += __shfl_xor(ss, 1, 16);
    ss += __shfl_xor(ss, 2, 16);
    ss += __shfl_xor(ss, 4, 16);
    ss += __shfl_xor(ss, 8, 16);
    if (cg == 0) {
        if (isx) xc[row] = -0.5f * ss * L2E;
        else     mc[row] = (logf(w[row]) - 0.5f * ss) * L2E;
    }
}

// ---------------------------------------------------------------------------
// Main MFMA kernel — FINAL = v21 (round-11 proven: 65.7 µs, absmax
// 2.524e-29): v17 counted-vmcnt tri-buffer + XCD-chunked swizzle.
// 512 thr, 128x256 tile, 8 waves 2x4, single-pass fp16, 4 K-phases,
// THREE staging buffers (A 3x8K, B 3x16K), counted vmcnt(3) (never 0 in the
// loop), raw s_barrier, prefetch depth 2; epilogue S[128x68] reduction +
// one atomic per (block,m).
// 13 rounds of structural exploration closed every axis: occupancy hints
// (null), 4-wave domains (null, reg-capped), XCD swizzle (null, L3 absorbs
// B), all-global K-loop (+17 µs), hybrid A-global (+7 µs), persistent
// multi-tile (register spill). Plateau: MFMA 20% / VALU 56% / LDS ~40% /
// HBM 2.4% — multi-pipe overlap floor for this decomposition.
// ---------------------------------------------------------------------------
__global__ __launch_bounds__(512, 4) void gmm_mfma(
    const short* __restrict__ Acat, const short* __restrict__ Bcat,
    const float* __restrict__ xc, const float* __restrict__ mc,
    float* __restrict__ out)
{
    __shared__ __align__(16) short smem[36864];   // 72 KB: A 3x4096 | B 3x8192
    __shared__ float red[4][128];

#define AS(b) (smem + (b) * 4096)
#define BS(b) (smem + 12288 + (b) * 8192)

    const int tid  = threadIdx.x;
    const int w    = tid >> 6, lane = tid & 63;   // w 0..7
    const int wm   = w >> 2,   wn   = w & 3;      // 2 x 4 wave grid
    const int quad = lane >> 4, col = lane & 15;

    // XCD-chunked swizzle (T1): bijective remap of the 4096-block grid
    const int g  = blockIdx.x + blockIdx.y * (MM / 128);
    const int k  = g & 7, j = g >> 3;
    const int bx = k * 16 + (j & 15);             // 0..127
    const int by = j >> 4;                        // 0..31
    const int m0 = bx * 128;
    const int nb = by * 256;

    // staging: wave w owns A row-block w (1 async16/group) and
    // B row-blocks {2w, 2w+1} (2 async16/group)
    const short* ga  = Acat + (size_t)(bx * 8 + w) * 2048 + lane * 8;
    const short* gb0 = Bcat + (size_t)(by * 16 + w * 2) * 2048 + lane * 8;
    const short* gb1 = gb0 + 2048;
    const int aofs  = w * 512;
    const int bofs0 = w * 1024;
    const int bofs1 = w * 1024 + 512;

    // epilogue constants loaded and CONSUMED into acc init before any DMA,
    // so the in-loop vmcnt counts staging groups only.
    float mcv[4];
    #pragma unroll
    for (int jj = 0; jj < 4; ++jj) mcv[jj] = mc[nb + wn * 64 + jj * 16 + col];
    float xa[4][4];
    #pragma unroll
    for (int i = 0; i < 4; ++i) {
        float4 xv = *(const float4*)(xc + m0 + wm * 64 + i * 16 + quad * 4);
        xa[i][0] = xv.x; xa[i][1] = xv.y; xa[i][2] = xv.z; xa[i][3] = xv.w;
    }

    // acc init = xa[r] + mcv[j]  (C/D layout: col=lane&15, row=quad*4+reg)
    f32x4 acc[4][4];
    #pragma unroll
    for (int i = 0; i < 4; ++i)
        #pragma unroll
        for (int jj = 0; jj < 4; ++jj)
            acc[i][jj] = (f32x4){xa[i][0] + mcv[jj], xa[i][1] + mcv[jj],
                                 xa[i][2] + mcv[jj], xa[i][3] + mcv[jj]};

    // drain the scalar/vector loads above -> vmcnt==0 entering the pipeline
    asm volatile("s_waitcnt vmcnt(0)" ::: "memory");
    __builtin_amdgcn_sched_barrier(0);

    // prologue: groups 0 and 1 (3 DMAs each per wave; 6 outstanding)
    async16(AS(0) + aofs,  ga);
    async16(BS(0) + bofs0, gb0);
    async16(BS(0) + bofs1, gb1);
    async16(AS(1) + aofs,  ga  + 512);
    async16(BS(1) + bofs0, gb0 + 512);
    async16(BS(1) + bofs1, gb1 + 512);

    // swizzled in-tile read offset (shorts): r'=col, g=quad
    const int rdo = col * 32 + ((quad + (col >> 1)) & 3) * 8;

#define COMPUTE(as_, bs_)                                                     \
    {                                                                         \
        const short* as = (as_);                                              \
        const short* bs = (bs_);                                              \
        f16x8 af[4];                                                          \
        _Pragma("unroll")                                                     \
        for (int i = 0; i < 4; ++i)                                           \
            af[i] = *(const f16x8*)(as + (wm * 4 + i) * 512 + rdo);           \
        _Pragma("unroll")                                                     \
        for (int jj = 0; jj < 4; ++jj) {                                      \
            f16x8 bfr = *(const f16x8*)(&bs[(wn * 4 + jj) * 512 + rdo]);      \
            _Pragma("unroll")                                                 \
            for (int i = 0; i < 4; ++i)                                       \
                acc[i][jj] = __builtin_amdgcn_mfma_f32_16x16x32_f16(          \
                    af[i], bfr, acc[i][jj], 0, 0, 0);                         \
        }                                                                     \
    }

    // ---- phase 0: outstanding {g0,g1}; need g0 -> vmcnt(3) ----
    asm volatile("s_waitcnt vmcnt(3)" ::: "memory");
    __builtin_amdgcn_sched_barrier(0);
    __builtin_amdgcn_s_barrier();
    __builtin_amdgcn_sched_barrier(0);
    async16(AS(2) + aofs,  ga  + 1024);     // group 2 -> buf 2
    async16(BS(2) + bofs0, gb0 + 1024);
    async16(BS(2) + bofs1, gb1 + 1024);
    COMPUTE(AS(0), BS(0));

    // ---- phase 1: outstanding {g1,g2}; need g1 -> vmcnt(3) ----
    asm volatile("s_waitcnt vmcnt(3)" ::: "memory");
    __builtin_amdgcn_sched_barrier(0);
    __builtin_amdgcn_s_barrier();
    __builtin_amdgcn_sched_barrier(0);
    async16(AS(0) + aofs,  ga  + 1536);     // group 3 -> buf 0 (read phase 0)
    async16(BS(0) + bofs0, gb0 + 1536);
    async16(BS(0) + bofs1, gb1 + 1536);
    COMPUTE(AS(1), BS(1));

    // ---- phase 2: outstanding {g2,g3}; need g2 -> vmcnt(3) ----
    asm volatile("s_waitcnt vmcnt(3)" ::: "memory");
    __builtin_amdgcn_sched_barrier(0);
    __builtin_amdgcn_s_barrier();
    __builtin_amdgcn_sched_barrier(0);
    COMPUTE(AS(2), BS(2));

    // ---- phase 3: outstanding {g3}; need g3 -> vmcnt(0) ----
    asm volatile("s_waitcnt vmcnt(0)" ::: "memory");
    __builtin_amdgcn_sched_barrier(0);
    __builtin_amdgcn_s_barrier();
    __builtin_amdgcn_sched_barrier(0);
    COMPUTE(AS(0), BS(0));
#undef COMPUTE

    // ---- epilogue (unchanged, proven) ----
    // 1) per-thread j-summed exp2 partials (arg fully pre-folded into acc)
    float sv[4][4];
    #pragma unroll
    for (int i = 0; i < 4; ++i) {
        #pragma unroll
        for (int r = 0; r < 4; ++r) {
            float s = 0.f;
            #pragma unroll
            for (int jj = 0; jj < 4; ++jj)
                s += __builtin_exp2f(acc[i][jj][r]);
            sv[i][r] = s;
        }
    }
    // 2) scatter to S[m_local][p] (aliases dead K-loop staging; stride 68
    //    floats -> 2-way bank aliasing on writes = free)
    __syncthreads();   // full drain: all K-loop LDS reads/DMAs complete
    {
        float* S = (float*)smem;
        const int p = wn * 16 + col;
        #pragma unroll
        for (int i = 0; i < 4; ++i) {
            const int mb = wm * 64 + i * 16 + quad * 4;
            #pragma unroll
            for (int r = 0; r < 4; ++r)
                S[(mb + r) * 68 + p] = sv[i][r];
        }
    }
    __syncthreads();
    // 3) 512 threads: row-contiguous b128 re-read, 16-way sum -> red[pg][m]
    {
        const float* S = (const float*)smem;
        const int m  = tid & 127;
        const int pg = tid >> 7;
        const float4* v = (const float4*)(S + m * 68 + pg * 16);
        float4 a0 = v[0], a1 = v[1], a2 = v[2], a3 = v[3];
        red[pg][m] = (a0.x + a0.y + a0.z + a0.w) + (a1.x + a1.y + a1.z + a1.w)
                   + (a2.x + a2.y + a2.z + a2.w) + (a3.x + a3.y + a3.z + a3.w);
    }
    __syncthreads();
    // 4) fused final reduction: one atomic per (block, m)
    if (tid < 128)
        atomicAdd(out + m0 + tid,
                  COEF * (red[0][tid] + red[1][tid] + red[2][tid] + red[3][tid]));
#undef AS
#undef BS
}

// ===========================================================================
// Fallback fp32 path (round-1) — only if ws_size is too small.
// ===========================================================================
__global__ __launch_bounds__(256) void gmm_prep(
    const float* __restrict__ x, const float* __restrict__ means,
    const float* __restrict__ w, float* __restrict__ xc, float* __restrict__ mc)
{
    int tid = blockIdx.x * 256 + threadIdx.x;
    if (tid < MM) {
        const float4* row = (const float4*)(x + (size_t)tid * DD);
        float ss = 0.f;
        #pragma unroll
        for (int i = 0; i < DD / 4; ++i) {
            float4 v = row[i];
            ss = fmaf(v.x, v.x, fmaf(v.y, v.y, fmaf(v.z, v.z, fmaf(v.w, v.w, ss))));
        }
        xc[tid] = -0.5f * ss * L2E;
    } else if (tid < MM + NN) {
        int n = tid - MM;
        const float4* row = (const float4*)(means + (size_t)n * DD);
        float ss = 0.f;
        #pragma unroll
        for (int i = 0; i < DD / 4; ++i) {
            float4 v = row[i];
            ss = fmaf(v.x, v.x, fmaf(v.y, v.y, fmaf(v.z, v.z, fmaf(v.w, v.w, ss))));
        }
        mc[n] = (logf(w[n]) - 0.5f * ss) * L2E;
    }
}

__global__ __launch_bounds__(256, 2) void gmm_main(
    const float* __restrict__ x, const float* __restrict__ means,
    const float* __restrict__ xc, const float* __restrict__ mc,
    float* __restrict__ out)
{
    __shared__ __align__(16) float Asm[128 * 128];
    __shared__ __align__(16) float Bsm[2][16 * 128];

    const int t   = threadIdx.x;
    const int tc  = t & 15;
    const int tr  = t >> 4;
    const int r0  = blockIdx.x * 128;
    const int nq0 = blockIdx.y * 2048;

    {
        float4 tmp[16];
        #pragma unroll
        for (int ii = 0; ii < 16; ++ii) {
            int idx = t + ii * 256;
            int r   = idx >> 5;
            int k0  = (idx & 31) << 2;
            tmp[ii] = *(const float4*)(x + (size_t)(r0 + r) * DD + k0);
        }
        #pragma unroll
        for (int ii = 0; ii < 16; ++ii) {
            int idx = t + ii * 256;
            int r   = idx >> 5;
            int k0  = (idx & 31) << 2;
            int rb  = r >> 3, rl = r & 7;
            float v[4] = {tmp[ii].x, tmp[ii].y, tmp[ii].z, tmp[ii].w};
            #pragma unroll
            for (int j = 0; j < 4; ++j) {
                int k = k0 + j;
                Asm[k * 128 + (((rb ^ (k & 15)) << 3) | rl)] = v[j];
            }
        }
    }

    float xcv[8];
    {
        float4 a = *(const float4*)(xc + r0 + tr * 8);
        float4 b = *(const float4*)(xc + r0 + tr * 8 + 4);
        xcv[0] = a.x; xcv[1] = a.y; xcv[2] = a.z; xcv[3] = a.w;
        xcv[4] = b.x; xcv[5] = b.y; xcv[6] = b.z; xcv[7] = b.w;
    }

    float rowAcc[8];
    #pragma unroll
    for (int i = 0; i < 8; ++i) rowAcc[i] = 0.f;

    for (int ntile = 0; ntile < 16; ++ntile) {
        const int nbase = nq0 + ntile * 128;

        float acc[8][8];
        #pragma unroll
        for (int i = 0; i < 8; ++i)
            #pragma unroll
            for (int j = 0; j < 8; ++j) acc[i][j] = 0.f;

        float4 ld[2];
        #pragma unroll
        for (int ii = 0; ii < 2; ++ii) {
            int flat = t + ii * 256;
            int nl   = flat >> 2;
            int kl   = (flat & 3) << 2;
            ld[ii] = *(const float4*)(means + (size_t)(nbase + nl) * DD + kl);
        }

        for (int ks = 0; ks < 8; ++ks) {
            const int buf = ks & 1;
            #pragma unroll
            for (int ii = 0; ii < 2; ++ii) {
                int flat = t + ii * 256;
                int nl   = flat >> 2;
                int k0   = (flat & 3) << 2;
                int nbk  = nl >> 3, nll = nl & 7;
                float v[4] = {ld[ii].x, ld[ii].y, ld[ii].z, ld[ii].w};
                #pragma unroll
                for (int j = 0; j < 4; ++j) {
                    int kl = k0 + j;
                    Bsm[buf][kl * 128 + (((nbk ^ kl) << 3) | nll)] = v[j];
                }
            }
            if (ks < 7) {
                #pragma unroll
                for (int ii = 0; ii < 2; ++ii) {
                    int flat = t + ii * 256;
                    int nl   = flat >> 2;
                    int kl   = (flat & 3) << 2;
                    ld[ii] = *(const float4*)(means + (size_t)(nbase + nl) * DD
                                              + (ks + 1) * 16 + kl);
                }
            }
            __syncthreads();

            #pragma unroll
            for (int kk = 0; kk < 16; ++kk) {
                const int k = ks * 16 + kk;
                const float* apx = &Asm[k * 128 + ((tr ^ kk) << 3)];
                float4 a0 = *(const float4*)apx;
                float4 a1 = *(const float4*)(apx + 4);
                const float* bpx = &Bsm[buf][kk * 128 + ((tc ^ kk) << 3)];
                float4 b0 = *(const float4*)bpx;
                float4 b1 = *(const float4*)(bpx + 4);
                float av[8] = {a0.x, a0.y, a0.z, a0.w, a1.x, a1.y, a1.z, a1.w};
                float bv[8] = {b0.x, b0.y, b0.z, b0.w, b1.x, b1.y, b1.z, b1.w};
                #pragma unroll
                for (int i = 0; i < 8; ++i)
                    #pragma unroll
                    for (int j = 0; j < 8; ++j)
                        acc[i][j] = fmaf(av[i], bv[j], acc[i][j]);
            }
        }

        float mcv[8];
        {
            float4 a = *(const float4*)(mc + nbase + tc * 8);
            float4 b = *(const float4*)(mc + nbase + tc * 8 + 4);
            mcv[0] = a.x; mcv[1] = a.y; mcv[2] = a.z; mcv[3] = a.w;
            mcv[4] = b.x; mcv[5] = b.y; mcv[6] = b.z; mcv[7] = b.w;
        }
        #pragma unroll
        for (int i = 0; i < 8; ++i) {
            float s = 0.f;
            #pragma unroll
            for (int j = 0; j < 8; ++j) {
                float arg = fmaf(acc[i][j], L2E, xcv[i] + mcv[j]);
                s += __builtin_exp2f(arg);
            }
            rowAcc[i] += s;
        }
    }

    #pragma unroll
    for (int i = 0; i < 8; ++i) {
        float v = rowAcc[i];
        v += __shfl_xor(v, 1, 16);
        v += __shfl_xor(v, 2, 16);
        v += __shfl_xor(v, 4, 16);
        v += __shfl_xor(v, 8, 16);
        if (tc == 0) atomicAdd(out + r0 + tr * 8 + i, COEF * v);
    }
}

extern "C" void kernel_launch(void* const* d_in, const int* in_sizes, int n_in,
                              void* d_out, int out_size, void* d_ws, size_t ws_size,
                              hipStream_t stream) {
    const float* x     = (const float*)d_in[0];
    const float* means = (const float*)d_in[1];
    const float* w     = (const float*)d_in[2];
    float* out = (float*)d_out;

    const size_t needA = (size_t)MM * 128 * sizeof(short);   // 4.2 MB
    const size_t needB = (size_t)NN * 128 * sizeof(short);   // 2.1 MB (dedup)
    const size_t need  = needA + needB + (size_t)(MM + NN) * 4;

    if (ws_size >= need) {
        short* Acat = (short*)d_ws;
        short* Bcat = Acat + (size_t)MM * 128;
        float* xc   = (float*)(Bcat + (size_t)NN * 128);
        float* mc   = xc + MM;
        hipMemsetAsync(out, 0, MM * sizeof(float), stream);
        gmm_prep_f16<<<(MM + NN) / 16, 256, 0, stream>>>(x, means, w, Acat, Bcat, xc, mc);
        gmm_mfma<<<dim3(MM / 128, NN / 256), 512, 0, stream>>>(Acat, Bcat, xc, mc, out);
    } else {
        float* xc = (float*)d_ws;
        float* mc = xc + MM;
        hipMemsetAsync(out, 0, MM * sizeof(float), stream);
        gmm_prep<<<(MM + NN + 255) / 256, 256, 0, stream>>>(x, means, w, xc, mc);
        gmm_main<<<dim3(MM / 128, 4), 256, 0, stream>>>(x, means, xc, mc, out);
    }
}